// Round 6
// baseline (449.314 us; speedup 1.0000x reference)
//
#include <hip/hip_runtime.h>

using u16 = unsigned short;
using f32x16 = __attribute__((ext_vector_type(16))) float;
using short8 = __attribute__((ext_vector_type(8))) short;

__device__ __forceinline__ float bf2f(u16 u) {
    union { unsigned int i; float f; } v; v.i = ((unsigned int)u) << 16; return v.f;
}
__device__ __forceinline__ u16 f2bf(float f) {
    union { float f; unsigned int i; } v; v.f = f;
    unsigned int u = v.i;
    u += 0x7fffu + ((u >> 16) & 1u);
    return (u16)(u >> 16);
}
__device__ __forceinline__ void gload16(const u16* g, u16* l) {
    __builtin_amdgcn_global_load_lds((const __attribute__((address_space(1))) void*)g,
                                     (__attribute__((address_space(3))) void*)l, 16, 0, 0);
}

// ---------------- fused prep: weight transposes + ssum + bias MLP ----------------
// wqkvt [1536][512]: n<512 -> Wq[c][n]; else Wkv[c][n-512]
// wot   [512][512]:  Wo^T
// winp  [2816][512]: col-permuted Win^T: 64-row group g = 32 val rows (jj=g*32+(n&31)) then 32 gate rows
// woutt [512][1408]: Wout^T * chan_g, K padded 1365->1408 with zeros
// then ssum (128 blocks x 4 warps) and bias MLP (256 blocks)
__global__ __launch_bounds__(256) void prep_all(
    const float* __restrict__ Wq, const float* __restrict__ Wkv,
    const float* __restrict__ Wo, const float* __restrict__ Win,
    const float* __restrict__ Wout, const float* __restrict__ cg,
    const float* __restrict__ w1, const float* __restrict__ b1,
    const float* __restrict__ w2, const float* __restrict__ b2,
    const float* __restrict__ w3, const float* __restrict__ b3,
    u16* __restrict__ wqkvt, u16* __restrict__ wot,
    u16* __restrict__ winp, u16* __restrict__ woutt,
    float* __restrict__ ssum, float* __restrict__ bias)
{
    if (blockIdx.x < 12544) {
        int i = blockIdx.x * 256 + threadIdx.x;
        if (i < 1536 * 512) {
            int n = i >> 9, c = i & 511;
            float v = (n < 512) ? Wq[c * 512 + n] : Wkv[c * 1024 + (n - 512)];
            wqkvt[i] = f2bf(v); return;
        }
        i -= 1536 * 512;
        if (i < 512 * 512) {
            int cc = i >> 9, k = i & 511;
            wot[i] = f2bf(Wo[k * 512 + cc]); return;
        }
        i -= 512 * 512;
        if (i < 2816 * 512) {
            int n = i >> 9, c = i & 511;
            int g = n >> 6, within = n & 63;
            int gate = within >> 5;
            int jj = (g << 5) + (within & 31);
            float v = (jj < 1365) ? Win[c * 2730 + jj + gate * 1365] : 0.f;
            winp[i] = f2bf(v); return;
        }
        i -= 2816 * 512;
        if (i < 512 * 1408) {
            int cc = i / 1408, j = i % 1408;
            float v = (j < 1365) ? Wout[j * 512 + cc] * cg[j] : 0.f;
            woutt[i] = f2bf(v); return;
        }
        return;
    }
    if (blockIdx.x < 12544 + 128) {
        int c = ((blockIdx.x - 12544) << 2) + (threadIdx.x >> 6);
        int lane = threadIdx.x & 63;
        float s = 0.f;
        for (int j = lane; j < 1365; j += 64) s += Wout[j * 512 + c] * cg[j];
        for (int off = 32; off; off >>= 1) s += __shfl_xor(s, off);
        if (lane == 0) ssum[c] = s;
        return;
    }
    {
        __shared__ float h1[256], h2[256];
        int rc = blockIdx.x - 12544 - 128;
        int ti = rc >> 4, tj = rc & 15;
        int j = threadIdx.x;
        float r = (float)(ti - tj);
        float rl = (r > 0.f) ? logf(r + 1.f) : ((r < 0.f) ? -logf(1.f - r) : 0.f);
        float a = rl * w1[j] + b1[j];
        h1[j] = a / (1.f + __expf(-a));
        __syncthreads();
        float acc = b2[j];
        for (int k = 0; k < 256; ++k) acc += h1[k] * w2[k * 256 + j];
        h2[j] = acc / (1.f + __expf(-acc));
        __syncthreads();
        if (j < 8) {
            float ab = b3[j];
            for (int k = 0; k < 256; ++k) ab += h2[k] * w3[k * 8 + j];
            bias[j * 256 + ti * 16 + tj] = ab;
        }
    }
}

// ---------------- K1: temporal LayerNorm, write xn & xt token-major bf16 ----------------
__global__ __launch_bounds__(256) void k1_norm(
    const float* __restrict__ x, const int* __restrict__ frp,
    const float* __restrict__ g_norm, const float* __restrict__ pos_emb,
    const float* __restrict__ fr_emb,
    u16* __restrict__ xn, u16* __restrict__ xt)
{
    __shared__ u16 tile[256 * 34];
    const int bid = blockIdx.x;
    const int b = bid >> 10, rem = bid & 1023;
    const int hw0 = (rem >> 4) << 4;
    const int c0 = (rem & 15) << 5;
    const int tid = threadIdx.x;
    const int hwl = tid & 15, cl = tid >> 4;
    const int fr = frp[0] - 1;
    float v[2][16], mean2[2], ri2[2], gg2[2], fv2[2];
    for (int cp = 0; cp < 2; ++cp) {
        const int c = c0 + cl + (cp << 4);
        const float* xp = x + (size_t)(b * 512 + c) * 16384 + hw0 + hwl;
        const float fv = fr_emb[fr * 512 + c];
        float s1 = 0.f, s2 = 0.f;
#pragma unroll
        for (int t = 0; t < 16; ++t) {
            float xv = xp[t * 1024];
            v[cp][t] = xv;
            float xe = xv + pos_emb[t * 512 + c] + fv;
            s1 += xe; s2 += xe * xe;
        }
        float m = s1 * 0.0625f;
        float var = s2 * 0.0625f - m * m;
        mean2[cp] = m; ri2[cp] = rsqrtf(fmaxf(var, 1e-5f));
        gg2[cp] = g_norm[c]; fv2[cp] = fv;
    }
    for (int cp = 0; cp < 2; ++cp) {
        const int c = c0 + cl + (cp << 4);
#pragma unroll
        for (int t = 0; t < 16; ++t) {
            float xe = v[cp][t] + pos_emb[t * 512 + c] + fv2[cp];
            tile[((t << 4) + hwl) * 34 + cl + (cp << 4)] = f2bf((xe - mean2[cp]) * ri2[cp] * gg2[cp]);
        }
    }
    __syncthreads();
    for (int it = 0; it < 32; ++it) {
        int rowl = (tid >> 5) + (it << 3);
        int col = tid & 31;
        size_t p = (size_t)b * 16384 + (size_t)(rowl >> 4) * 1024 + hw0 + (rowl & 15);
        xn[p * 512 + c0 + col] = tile[rowl * 34 + col];
    }
    __syncthreads();
    for (int cp = 0; cp < 2; ++cp)
#pragma unroll
        for (int t = 0; t < 16; ++t)
            tile[((t << 4) + hwl) * 34 + cl + (cp << 4)] = f2bf(v[cp][t]);
    __syncthreads();
    for (int it = 0; it < 32; ++it) {
        int rowl = (tid >> 5) + (it << 3);
        int col = tid & 31;
        size_t p = (size_t)b * 16384 + (size_t)(rowl >> 4) * 1024 + hw0 + (rowl & 15);
        xt[p * 512 + c0 + col] = tile[rowl * 34 + col];
    }
}

// ---------------- generic MFMA GEMM: C[M=32768][N] = A[M][K] * B^T[N][K] ----------------
// 128x128 tile, 256 thr, 2-barrier structure + XCD-chunked swizzle.
// Inner loop: v_mfma_f32_32x32x16_bf16, per-wave 64x64 = 2x2 fragments of 32x32.
// A/B operand: lane holds row (lane&31), k-chunk (lane>>5)*8 (8 contiguous bf16).
// C/D: col=lane&31, row=(reg&3)+8*(reg>>2)+4*(lane>>5).
// EPI 3 computes per-row channel-LN stats inline from av fragments (wc==0 waves).
template<int EPI>
__global__ __launch_bounds__(256, 2) void gemm_bt(
    const u16* __restrict__ A, const u16* __restrict__ B, int K, int Nb,
    u16* __restrict__ outb, float* __restrict__ outf,
    const u16* __restrict__ addb,
    const float* __restrict__ ssum, int ldOut)
{
    __shared__ u16 lds[2 * 128 * 64];
    __shared__ float smr[256];          // EPI3: [0:128) mean, [128:256) rinv
    u16* lA = lds;
    u16* lB = lds + 128 * 64;
    const int tid = threadIdx.x, lane = tid & 63, w = tid >> 6;
    const int wr = w >> 1, wc = w & 1;
    const int l31 = lane & 31, hi = lane >> 5;
    const int cpx = gridDim.x >> 3;
    const int wgid = (blockIdx.x & 7) * cpx + (blockIdx.x >> 3);
    const int p0 = (wgid / Nb) * 128, n0 = (wgid % Nb) * 128;
    f32x16 acc[2][2] = {};
    float sst[2] = {}, sq[2] = {};

    auto rdA = [&](int mf, int ks) -> short8 {
        int r = wr * 64 + mf * 32 + l31;
        int cc = ((ks << 1) + hi) ^ (r & 7);
        return *(const short8*)(lA + r * 64 + cc * 8);
    };
    auto rdB = [&](int nf, int ks) -> short8 {
        int r = wc * 64 + nf * 32 + l31;
        int cc = ((ks << 1) + hi) ^ (r & 7);
        return *(const short8*)(lB + r * 64 + cc * 8);
    };

    for (int kt = 0; kt < K; kt += 64) {
        for (int i = 0; i < 4; ++i) {
            int rb = w * 4 + i;
            int r = rb * 8 + (lane >> 3);
            int cg = (lane & 7) ^ (r & 7);
            gload16(A + (size_t)(p0 + r) * K + (kt + cg * 8), lA + rb * 512);
            gload16(B + (size_t)(n0 + r) * K + (kt + cg * 8), lB + rb * 512);
        }
        __syncthreads();
#pragma unroll
        for (int ks = 0; ks < 4; ++ks) {
            short8 av[2], bv[2];
            av[0] = rdA(0, ks); av[1] = rdA(1, ks);
            bv[0] = rdB(0, ks); bv[1] = rdB(1, ks);
            if constexpr (EPI == 3) {
                if (wc == 0) {
#pragma unroll
                    for (int mf = 0; mf < 2; ++mf)
#pragma unroll
                        for (int j = 0; j < 8; ++j) {
                            float v = bf2f((u16)av[mf][j]);
                            sst[mf] += v; sq[mf] += v * v;
                        }
                }
            }
#pragma unroll
            for (int mf = 0; mf < 2; ++mf)
#pragma unroll
                for (int nf = 0; nf < 2; ++nf)
                    acc[mf][nf] = __builtin_amdgcn_mfma_f32_32x32x16_bf16(av[mf], bv[nf], acc[mf][nf], 0, 0, 0);
        }
        __syncthreads();
    }

    if constexpr (EPI == 0 || EPI == 1) {
#pragma unroll
        for (int mf = 0; mf < 2; ++mf)
#pragma unroll
            for (int nf = 0; nf < 2; ++nf) {
                int col = n0 + wc * 64 + nf * 32 + l31;
#pragma unroll
                for (int q = 0; q < 4; ++q) {
                    int row = p0 + wr * 64 + mf * 32 + q * 8 + (hi << 2);
#pragma unroll
                    for (int r2 = 0; r2 < 4; ++r2) {
                        float vv = acc[mf][nf][q * 4 + r2];
                        if constexpr (EPI == 1) vv += bf2f(addb[(size_t)(row + r2) * ldOut + col]);
                        outb[(size_t)(row + r2) * ldOut + col] = f2bf(vv);
                    }
                }
            }
    } else if constexpr (EPI == 2) {
        const int colV = n0 + wc * 64 + l31;           // val fragment col (nf=0)
        const int jj = ((colV >> 6) << 5) + (colV & 31);
        const int t = (p0 >> 10) & 15;
#pragma unroll
        for (int mf = 0; mf < 2; ++mf)
#pragma unroll
            for (int q = 0; q < 4; ++q) {
                int rowb = p0 + wr * 64 + mf * 32 + q * 8 + (hi << 2);
#pragma unroll
                for (int r2 = 0; r2 < 4; ++r2) {
                    int p = rowb + r2;
                    float vv = acc[mf][0][q * 4 + r2], gv = acc[mf][1][q * 4 + r2];
                    float glu = vv * 0.5f * gv * (1.f + erff(gv * 0.70710678f));
                    if (jj >= 1365) {
                        outb[(size_t)p * 1408 + jj] = 0;
                    } else if (jj >= 683) {
                        if (t < 15) outb[(size_t)(p + 1024) * 1408 + jj] = f2bf(glu);
                        if (t == 0) outb[(size_t)p * 1408 + jj] = 0;
                    } else {
                        outb[(size_t)p * 1408 + jj] = f2bf(glu);
                    }
                }
            }
    } else {
        // EPI 3: finish inline stats, then channel-LN apply + residual + transposed fp32 store
        if (wc == 0) {
#pragma unroll
            for (int mf = 0; mf < 2; ++mf) {
                float s = sst[mf], q = sq[mf];
                s += __shfl_xor(s, 32); q += __shfl_xor(q, 32);
                if (hi == 0) {
                    int row = wr * 64 + mf * 32 + l31;
                    smr[row] = s; smr[128 + row] = q;
                }
            }
        }
        __syncthreads();
        if (tid < 128) {
            float mm = smr[tid] * (1.f / 1365.f);
            float var = smr[128 + tid] * (1.f / 1365.f) - mm * mm;
            smr[tid] = mm;
            smr[128 + tid] = rsqrtf(fmaxf(var, 1e-5f));
        }
        float* ldsT = (float*)lds;
        const int bb = p0 >> 14, tt = (p0 >> 10) & 15, hwb = p0 & 1023;
        float* outp = outf + (size_t)bb * 8388608 + (size_t)tt * 1024 + hwb;
        for (int cg4 = 0; cg4 < 4; ++cg4) {
            __syncthreads();
            if (wc == (cg4 >> 1)) {
                int nf = cg4 & 1;
                int col = n0 + wc * 64 + nf * 32 + l31;
                float ssv = ssum[col];
#pragma unroll
                for (int mf = 0; mf < 2; ++mf)
#pragma unroll
                    for (int q = 0; q < 4; ++q) {
                        int rl = wr * 64 + mf * 32 + q * 8 + (hi << 2);
#pragma unroll
                        for (int r2 = 0; r2 < 4; ++r2) {
                            int p = p0 + rl + r2;
                            float vv = smr[128 + rl + r2] * (acc[mf][nf][q * 4 + r2] - smr[rl + r2] * ssv)
                                     + bf2f(addb[(size_t)p * 512 + col]);
                            ldsT[l31 * 132 + rl + r2] = vv;
                        }
                    }
            }
            __syncthreads();
#pragma unroll
            for (int e = 0; e < 16; ++e) {
                int li = e * 256 + tid;
                int cl2 = li >> 7, hwl = li & 127;
                outp[(size_t)(n0 + cg4 * 32 + cl2) * 16384 + hwl] = ldsT[cl2 * 132 + hwl];
            }
        }
    }
}

// ---------------- attention: per (8-pixel chunk, head) block; 2 blocks/CU ----------------
__global__ __launch_bounds__(256, 2) void attn_kernel(
    const u16* __restrict__ qkv, const float* __restrict__ bias, u16* __restrict__ o)
{
    __shared__ u16 qkvt[3 * 128 * 64];     // 48 KB: rows r = t*8 + pix
    __shared__ float pl[128 * 17];         // 8.5 KB score/prob rows
    __shared__ float bl[256];
    const int tid = threadIdx.x, lane = tid & 63, w = tid >> 6;
    const int pc = blockIdx.x, h = blockIdx.y;
    const int b = pc >> 7, hw0 = (pc & 127) << 3;
    bl[tid] = bias[h * 256 + tid];
    for (int i = 0; i < 12; ++i) {
        int idx = w * 12 + i;              // 48 row-blocks of 8 rows (16 per s)
        int s = idx >> 4, rb = idx & 15;
        int r = (rb << 3) + (lane >> 3);
        int cg = (lane & 7) ^ (r & 7);
        size_t grow = (size_t)b * 16384 + (size_t)(r >> 3) * 1024 + hw0 + (r & 7);
        gload16(qkv + grow * 1536 + s * 512 + h * 64 + cg * 8, qkvt + s * 8192 + rb * 512);
    }
    __syncthreads();
    {
        const int qrow = tid & 127, hh = tid >> 7;
        const int pix = qrow & 7, ti = qrow >> 3;
        float qv[64];
        const u16* qr = qkvt + qrow * 64;
#pragma unroll
        for (int cc = 0; cc < 8; ++cc) {
            short8 qq = *(const short8*)(qr + ((cc ^ (qrow & 7)) << 3));
#pragma unroll
            for (int j = 0; j < 8; ++j) qv[cc * 8 + j] = bf2f((u16)qq[j]);
        }
#pragma unroll
        for (int tj8 = 0; tj8 < 8; ++tj8) {
            int tj = (hh << 3) + tj8;
            int rk = (tj << 3) + pix;
            const u16* kr = qkvt + 8192 + rk * 64;
            float a = 0.f;
#pragma unroll
            for (int cc = 0; cc < 8; ++cc) {
                short8 kk = *(const short8*)(kr + ((cc ^ (rk & 7)) << 3));
#pragma unroll
                for (int j = 0; j < 8; ++j) a += qv[cc * 8 + j] * bf2f((u16)kk[j]);
            }
            pl[qrow * 17 + tj] = a * 0.125f + bl[(ti << 4) + tj];
        }
    }
    __syncthreads();
    if (tid < 128) {
        float sc[16];
#pragma unroll
        for (int j = 0; j < 16; ++j) sc[j] = pl[tid * 17 + j];
        float mx = sc[0];
#pragma unroll
        for (int j = 1; j < 16; ++j) mx = fmaxf(mx, sc[j]);
        float sum = 0.f;
#pragma unroll
        for (int j = 0; j < 16; ++j) { sc[j] = __expf(sc[j] - mx); sum += sc[j]; }
        float inv = 1.f / sum;
#pragma unroll
        for (int j = 0; j < 16; ++j) pl[tid * 17 + j] = sc[j] * inv;
    }
    __syncthreads();
    {
        const int pix = tid >> 5, dg = tid & 31;
        float v0[16], v1[16];
#pragma unroll
        for (int tj = 0; tj < 16; ++tj) {
            int rv = (tj << 3) + pix;
            unsigned int d = *(const unsigned int*)(qkvt + 16384 + rv * 64 +
                               (((dg >> 2) ^ (rv & 7)) << 3) + ((dg & 3) << 1));
            v0[tj] = bf2f((u16)(d & 0xffff));
            v1[tj] = bf2f((u16)(d >> 16));
        }
#pragma unroll
        for (int ti = 0; ti < 16; ++ti) {
            float a0 = 0.f, a1 = 0.f;
            const float* pr = pl + ((ti << 3) + pix) * 17;
#pragma unroll
            for (int tj = 0; tj < 16; ++tj) {
                float pv = pr[tj];
                a0 += pv * v0[tj];
                a1 += pv * v1[tj];
            }
            size_t p = (size_t)b * 16384 + (size_t)ti * 1024 + hw0 + pix;
            unsigned int pk = (unsigned int)f2bf(a0) | ((unsigned int)f2bf(a1) << 16);
            *(unsigned int*)(o + p * 512 + h * 64 + (dg << 1)) = pk;
        }
    }
}

extern "C" void kernel_launch(void* const* d_in, const int* in_sizes, int n_in,
                              void* d_out, int out_size, void* d_ws, size_t ws_size,
                              hipStream_t stream)
{
    const float* x       = (const float*)d_in[0];
    const int*   frp     = (const int*)d_in[1];
    const float* g_norm  = (const float*)d_in[2];
    const float* Wq      = (const float*)d_in[3];
    const float* Wkv     = (const float*)d_in[4];
    const float* Wo      = (const float*)d_in[5];
    const float* pos_emb = (const float*)d_in[6];
    const float* fr_emb  = (const float*)d_in[7];
    const float* w1      = (const float*)d_in[8];
    const float* b1      = (const float*)d_in[9];
    const float* w2      = (const float*)d_in[10];
    const float* b2      = (const float*)d_in[11];
    const float* w3      = (const float*)d_in[12];
    const float* b3      = (const float*)d_in[13];
    const float* Win     = (const float*)d_in[14];
    const float* chan_g  = (const float*)d_in[15];
    const float* Wout    = (const float*)d_in[16];

    char* ws = (char*)d_ws;
    u16*   wqkvt = (u16*)(ws + 0);
    u16*   wot   = (u16*)(ws + 1572864);
    u16*   winp  = (u16*)(ws + 2097152);
    u16*   woutt = (u16*)(ws + 4980736);
    float* ssum  = (float*)(ws + 6422528);
    float* biasb = (float*)(ws + 6424576);
    u16*   qkv   = (u16*)(ws + 8388608);     // reused as yg after attention
    u16*   xn    = (u16*)(ws + 109051904);   // reused as o_att after qkv GEMM
    u16*   xt    = (u16*)(ws + 142606336);
    u16*   x2    = (u16*)(ws + 176160768);
    u16*   o_att = xn;
    u16*   yg    = qkv;

    prep_all<<<12544 + 128 + 256, 256, 0, stream>>>(
        Wq, Wkv, Wo, Win, Wout, chan_g, w1, b1, w2, b2, w3, b3,
        wqkvt, wot, winp, woutt, ssum, biasb);
    k1_norm<<<2048, 256, 0, stream>>>(x, frp, g_norm, pos_emb, fr_emb, xn, xt);
    gemm_bt<0><<<256 * 12, 256, 0, stream>>>(xn, wqkvt, 512, 12, qkv, nullptr, nullptr,
                                             nullptr, 1536);
    attn_kernel<<<dim3(256, 8), 256, 0, stream>>>(qkv, biasb, o_att);
    gemm_bt<1><<<256 * 4, 256, 0, stream>>>(o_att, wot, 512, 4, x2, nullptr, xt,
                                            nullptr, 512);
    gemm_bt<2><<<256 * 22, 256, 0, stream>>>(x2, winp, 512, 22, yg, nullptr, nullptr,
                                             nullptr, 1408);
    gemm_bt<3><<<256 * 4, 256, 0, stream>>>(yg, woutt, 1408, 4, nullptr, (float*)d_out, x2,
                                            ssum, 512);
}